// Round 7
// baseline (243.646 us; speedup 1.0000x reference)
//
#include <hip/hip_runtime.h>
#include <hip/hip_fp16.h>
#include <cstdint>
#include <cstddef>

#define NHEAD 16
#define HDIM  64
#define HID   1024

using f16x8 = __attribute__((ext_vector_type(8))) _Float16;
using f16x2 = __attribute__((ext_vector_type(2))) _Float16;
using f32x4 = __attribute__((ext_vector_type(4))) float;

typedef const __attribute__((address_space(1))) unsigned int* gq_t;
typedef __attribute__((address_space(3))) unsigned int* lq_t;

// ------------------------------------------------------- weight converter
// Weights Wq/Wk/Wv -> wqkv16, Wo -> wo16 (f16); bq|bk|bv -> bqkv (f32).
// x is NOT converted here anymore — the QKV GEMM converts A in-staging.
__global__ void cvt_w(const float* __restrict__ Wq, const float* __restrict__ Wk,
                      const float* __restrict__ Wv, const float* __restrict__ Wo,
                      const float* __restrict__ bq, const float* __restrict__ bk,
                      const float* __restrict__ bv,
                      _Float16* __restrict__ wqkv, _Float16* __restrict__ wo,
                      float* __restrict__ bqkv, int n8w)
{
    for (int i = blockIdx.x * blockDim.x + threadIdx.x; i < 4 * n8w; i += gridDim.x * blockDim.x) {
        const int seg = i / n8w;
        const size_t off = (size_t)(i - seg * n8w);
        const float* src = (seg == 0) ? Wq : (seg == 1) ? Wk : (seg == 2) ? Wv : Wo;
        _Float16* dst = (seg < 3) ? (wqkv + (size_t)seg * HID * HID) : wo;
        const float4* p = (const float4*)(src + off * 8);
        float4 a = p[0], b = p[1];
        f16x8 o;
        o[0] = (_Float16)a.x; o[1] = (_Float16)a.y; o[2] = (_Float16)a.z; o[3] = (_Float16)a.w;
        o[4] = (_Float16)b.x; o[5] = (_Float16)b.y; o[6] = (_Float16)b.z; o[7] = (_Float16)b.w;
        *(f16x8*)(dst + off * 8) = o;
    }
    const int bi = blockIdx.x * blockDim.x + threadIdx.x;
    if (bi < 384) {
        const int seg = bi >> 7;
        const int off = (bi & 127) * 8;
        const float* src = (seg == 0) ? bq : (seg == 1) ? bk : bv;
        const float4* p = (const float4*)(src + off);
        float4 a = p[0], b = p[1];
        float4* q = (float4*)(bqkv + seg * HID + off);
        q[0] = a; q[1] = b;
    }
}

// ------------------------------------------------------------------- GEMM
// C[M][N] = A[M][K] @ B[N][K]^T + bias[N]
// 128x128 tile, 4 waves (2x2), BK=64, XOR slot-swizzle (slot ^= row&7).
// CVT_A=false: A is f16, staged via global_load_lds (R4-proven: 0 conflicts,
//   110.5/37 us at 932 TF).
// CVT_A=true:  A is f32, reg-staged (load f32x8 -> v_cvt_pkrtz -> ds_write_b128
//   to slot s_l^(r&7), preserving the read-side swizzle invariant). Per
//   quarter-wave the ds_write covers 32 banks x 2 lanes = 2-way = free (m136).
template <typename OutT, bool CVT_A>
__global__ __launch_bounds__(256, 4)
void gemm_bt(const void* __restrict__ Av, const _Float16* __restrict__ Bw,
             const float* __restrict__ bias, OutT* __restrict__ C,
             int M, int N, int K)
{
    __shared__ _Float16 As[128 * 64];
    __shared__ _Float16 Bs[128 * 64];

    const int tid  = threadIdx.x;
    const int lane = tid & 63;
    const int wid  = tid >> 6;
    const int wm   = wid >> 1;   // 0..1
    const int wn   = wid & 1;    // 0..1
    const int m0   = blockIdx.y * 128;
    const int n0   = blockIdx.x * 128;

    f32x4 acc[4][4] = {};

    const int r_in  = lane >> 3;       // 0..7 row within wave's 8-row strip
    const int s_lds = lane & 7;        // 0..7 16B slot within row

    for (int k0 = 0; k0 < K; k0 += 64) {
        #pragma unroll
        for (int j = 0; j < 4; ++j) {
            const int rbase = j * 32 + wid * 8;       // wave-uniform
            const int r     = rbase + r_in;
            const int s_g   = s_lds ^ (r & 7);        // pre-swizzled global source
            if constexpr (CVT_A) {
                const float* ga = (const float*)Av + (size_t)(m0 + r) * K + k0 + s_lds * 8;
                float4 u = ((const float4*)ga)[0];
                float4 v = ((const float4*)ga)[1];
                auto p01 = __builtin_amdgcn_cvt_pkrtz(u.x, u.y);
                auto p23 = __builtin_amdgcn_cvt_pkrtz(u.z, u.w);
                auto p45 = __builtin_amdgcn_cvt_pkrtz(v.x, v.y);
                auto p67 = __builtin_amdgcn_cvt_pkrtz(v.z, v.w);
                f16x8 o;
                o[0] = p01[0]; o[1] = p01[1]; o[2] = p23[0]; o[3] = p23[1];
                o[4] = p45[0]; o[5] = p45[1]; o[6] = p67[0]; o[7] = p67[1];
                *(f16x8*)&As[r * 64 + s_g * 8] = o;   // write slot s_l^(r&7)
            } else {
                const _Float16* ga = (const _Float16*)Av + (size_t)(m0 + r) * K + k0 + s_g * 8;
                __builtin_amdgcn_global_load_lds((gq_t)(const void*)ga,
                                                 (lq_t)(void*)(As + rbase * 64), 16, 0, 0);
            }
            const _Float16* gb = Bw + (size_t)(n0 + r) * K + k0 + s_g * 8;
            __builtin_amdgcn_global_load_lds((gq_t)(const void*)gb,
                                             (lq_t)(void*)(Bs + rbase * 64), 16, 0, 0);
        }
        __syncthreads();

        const int g = lane >> 4;              // k-group 0..3
        #pragma unroll
        for (int kk = 0; kk < 2; ++kk) {
            f16x8 af[4], bf[4];
            #pragma unroll
            for (int mi = 0; mi < 4; ++mi) {
                const int row  = wm * 64 + mi * 16 + (lane & 15);
                const int slot = (kk * 4 + g) ^ (row & 7);
                af[mi] = *(const f16x8*)&As[row * 64 + slot * 8];
            }
            #pragma unroll
            for (int ni = 0; ni < 4; ++ni) {
                const int row  = wn * 64 + ni * 16 + (lane & 15);
                const int slot = (kk * 4 + g) ^ (row & 7);
                bf[ni] = *(const f16x8*)&Bs[row * 64 + slot * 8];
            }
            #pragma unroll
            for (int mi = 0; mi < 4; ++mi)
                #pragma unroll
                for (int ni = 0; ni < 4; ++ni)
                    acc[mi][ni] = __builtin_amdgcn_mfma_f32_16x16x32_f16(
                        af[mi], bf[ni], acc[mi][ni], 0, 0, 0);
        }
        __syncthreads();
    }

    #pragma unroll
    for (int ni = 0; ni < 4; ++ni) {
        const int col = n0 + wn * 64 + ni * 16 + (lane & 15);
        const float bv = bias[col];
        #pragma unroll
        for (int mi = 0; mi < 4; ++mi) {
            const int rowb = m0 + wm * 64 + mi * 16 + (lane >> 4) * 4;
            #pragma unroll
            for (int q = 0; q < 4; ++q) {
                const float val = acc[mi][ni][q] + bv;
                C[(size_t)(rowb + q) * N + col] = (OutT)val;
            }
        }
    }
}

// --------------------------------------------------------------- attention
// Per token: q,k,v in [16][64]; scores = (q*scale)@k^T / 8; softmax over t;
// out = attn @ v.  8 tokens/block, 128 threads: thread = (token, head-row h).
__global__ __launch_bounds__(128, 2)
void attn_kernel(const _Float16* __restrict__ qkv, const float* __restrict__ scale,
                 _Float16* __restrict__ out)
{
    __shared__ _Float16 kv[8][2048];   // per token: k[0..1024), v[1024..2048)
    __shared__ _Float16 sc2[64];       // scale * 0.125 in f16

    const int tid  = threadIdx.x;
    const int tok0 = blockIdx.x * 8;

    if (tid < 64) sc2[tid] = (_Float16)(scale[tid] * 0.125f);

    #pragma unroll
    for (int it = 0; it < 16; ++it) {
        const int vid = tid + it * 128;
        const int tok = vid >> 8;
        const int ofs = (vid & 255) * 8;
        *(f16x8*)&kv[tok][ofs] =
            *(const f16x8*)&qkv[(size_t)(tok0 + tok) * 3072 + 1024 + ofs];
    }
    __syncthreads();

    const int tok = tid >> 4;
    const int h   = tid & 15;
    const size_t qbase = (size_t)(tok0 + tok) * 3072 + h * 64;

    f16x2 q2[32];
    #pragma unroll
    for (int d0 = 0; d0 < 8; ++d0) {
        f16x8 qv = *(const f16x8*)&qkv[qbase + d0 * 8];
        f16x8 sv = *(const f16x8*)&sc2[d0 * 8];
        #pragma unroll
        for (int j = 0; j < 4; ++j) {
            f16x2 t;
            t[0] = qv[2 * j]     * sv[2 * j];
            t[1] = qv[2 * j + 1] * sv[2 * j + 1];
            q2[d0 * 4 + j] = t;
        }
    }

    float s[16];
    #pragma unroll
    for (int t = 0; t < 16; ++t) {
        float a = 0.f;
        #pragma unroll
        for (int p = 0; p < 32; ++p) {
            f16x2 kp = *(const f16x2*)&kv[tok][t * 64 + p * 2];
            a = __builtin_amdgcn_fdot2(q2[p], kp, a, false);
        }
        s[t] = a;
    }

    float mx = s[0];
    #pragma unroll
    for (int t = 1; t < 16; ++t) mx = fmaxf(mx, s[t]);
    float sum = 0.f;
    #pragma unroll
    for (int t = 0; t < 16; ++t) { s[t] = __expf(s[t] - mx); sum += s[t]; }
    const float inv = 1.f / sum;

    f16x2 o2[32] = {};
    #pragma unroll
    for (int t = 0; t < 16; ++t) {
        const _Float16 aw = (_Float16)(s[t] * inv);
        f16x2 aw2; aw2[0] = aw; aw2[1] = aw;
        #pragma unroll
        for (int p = 0; p < 32; ++p) {
            f16x2 vp = *(const f16x2*)&kv[tok][1024 + t * 64 + p * 2];
            o2[p] += aw2 * vp;     // v_pk_fma_f16
        }
    }

    #pragma unroll
    for (int d0 = 0; d0 < 8; ++d0) {
        f16x8 ov;
        #pragma unroll
        for (int j = 0; j < 4; ++j) { ov[2*j] = o2[d0*4+j][0]; ov[2*j+1] = o2[d0*4+j][1]; }
        *(f16x8*)&out[(size_t)(tok0 + tok) * 1024 + h * 64 + d0 * 8] = ov;
    }
}

// ----------------------------------------------------------------- launcher
extern "C" void kernel_launch(void* const* d_in, const int* in_sizes, int n_in,
                              void* d_out, int out_size, void* d_ws, size_t ws_size,
                              hipStream_t stream)
{
    const float* x     = (const float*)d_in[0];
    const float* Wq    = (const float*)d_in[1];
    const float* bq    = (const float*)d_in[2];
    const float* Wk    = (const float*)d_in[3];
    const float* bk    = (const float*)d_in[4];
    const float* Wv    = (const float*)d_in[5];
    const float* bv    = (const float*)d_in[6];
    const float* Wo    = (const float*)d_in[7];
    const float* bo    = (const float*)d_in[8];
    const float* scale = (const float*)d_in[9];
    float* out = (float*)d_out;

    const int M = in_sizes[0] / HID;   // 16384 tokens

    // workspace: attn16 | wqkv16 | wo16 | bqkv | qkv16
    char* ws = (char*)d_ws;
    _Float16* attn16 = (_Float16*)ws;
    _Float16* wqkv16 = (_Float16*)(ws + (size_t)M * HID * 2);
    _Float16* wo16   = wqkv16 + (size_t)3 * HID * HID;
    float*    bqkv   = (float*)(wo16 + (size_t)HID * HID);
    _Float16* qkv16  = (_Float16*)((char*)bqkv + 3 * HID * 4);

    cvt_w<<<2048, 256, 0, stream>>>(Wq, Wk, Wv, Wo, bq, bk, bv,
                                    wqkv16, wo16, bqkv, HID * HID / 8);

    // QKV GEMM: x f32 [M,1024] (A converted in-staging) @ [3072,1024]^T -> qkv16
    gemm_bt<_Float16, true><<<dim3(3 * HID / 128, M / 128), 256, 0, stream>>>(
        x, wqkv16, bqkv, qkv16, M, 3 * HID, HID);

    // per-token head-mix attention -> attn16 [M,1024] (f16)
    attn_kernel<<<M / 8, 128, 0, stream>>>(qkv16, scale, attn16);

    // output GEMM: [M,1024] @ [1024,1024]^T + bo -> out (f32)
    gemm_bt<float, false><<<dim3(HID / 128, M / 128), 256, 0, stream>>>(
        attn16, wo16, bo, out, M, HID, HID);
}

// Round 8
// 216.282 us; speedup vs baseline: 1.1265x; 1.1265x over previous
//
#include <hip/hip_runtime.h>
#include <hip/hip_fp16.h>
#include <cstdint>
#include <cstddef>

#define NHEAD 16
#define HDIM  64
#define HID   1024

using f16x8 = __attribute__((ext_vector_type(8))) _Float16;
using f16x2 = __attribute__((ext_vector_type(2))) _Float16;
using f32x4 = __attribute__((ext_vector_type(4))) float;

typedef const __attribute__((address_space(1))) unsigned int* gq_t;
typedef __attribute__((address_space(3))) unsigned int* lq_t;

// ------------------------------------------------------- fused converter
// x -> x16, Wq/Wk/Wv -> wqkv16, Wo -> wo16 (f16); bq|bk|bv -> bqkv (f32).
// (R7 measured: folding x-conversion into the GEMM costs +150MB refetch
//  and +60us — the explicit x16 round-trip at BW floor is cheaper.)
__global__ void cvt_all(const float* __restrict__ x,
                        const float* __restrict__ Wq, const float* __restrict__ Wk,
                        const float* __restrict__ Wv, const float* __restrict__ Wo,
                        const float* __restrict__ bq, const float* __restrict__ bk,
                        const float* __restrict__ bv,
                        _Float16* __restrict__ x16, _Float16* __restrict__ wqkv,
                        _Float16* __restrict__ wo, float* __restrict__ bqkv,
                        int n8x, int n8w)
{
    const int n8tot = n8x + 4 * n8w;
    for (int i = blockIdx.x * blockDim.x + threadIdx.x; i < n8tot; i += gridDim.x * blockDim.x) {
        const float* src;
        _Float16* dst;
        size_t off;
        if (i < n8x) {
            src = x; dst = x16; off = (size_t)i;
        } else {
            const int j = i - n8x;
            const int seg = j / n8w;
            off = (size_t)(j - seg * n8w);
            src = (seg == 0) ? Wq : (seg == 1) ? Wk : (seg == 2) ? Wv : Wo;
            dst = (seg < 3) ? (wqkv + (size_t)seg * HID * HID) : wo;
        }
        const float4* p = (const float4*)(src + off * 8);
        float4 a = p[0], b = p[1];
        f16x8 o;
        o[0] = (_Float16)a.x; o[1] = (_Float16)a.y; o[2] = (_Float16)a.z; o[3] = (_Float16)a.w;
        o[4] = (_Float16)b.x; o[5] = (_Float16)b.y; o[6] = (_Float16)b.z; o[7] = (_Float16)b.w;
        *(f16x8*)(dst + off * 8) = o;
    }
    const int bi = blockIdx.x * blockDim.x + threadIdx.x;
    if (bi < 384) {
        const int seg = bi >> 7;
        const int off = (bi & 127) * 8;
        const float* src = (seg == 0) ? bq : (seg == 1) ? bk : bv;
        const float4* p = (const float4*)(src + off);
        float4 a = p[0], b = p[1];
        float4* q = (float4*)(bqkv + seg * HID + off);
        q[0] = a; q[1] = b;
    }
}

// ------------------------------------------------------------------- GEMM
// C[M][N] = A[M][K] @ B[N][K]^T + bias[N]
// 128x128 tile, 4 waves (2x2), BK=64, global_load_lds staging both operands,
// XOR slot-swizzle (slot ^= row&7) -> measured 0 bank conflicts.
// Proven config: 110.5us QKV / 37us out (932 TF, m97-structure ceiling).
// Measured-worse alternatives: 32x32x16 MFMA (129us, 1.26e7 conflicts),
// 256^2 8-phase (717 TF x2 ports), f32-A reg-staged cvt (170us, 2x FETCH).
template <typename OutT>
__global__ __launch_bounds__(256, 4)
void gemm_bt(const _Float16* __restrict__ A, const _Float16* __restrict__ Bw,
             const float* __restrict__ bias, OutT* __restrict__ C,
             int M, int N, int K)
{
    __shared__ _Float16 As[128 * 64];
    __shared__ _Float16 Bs[128 * 64];

    const int tid  = threadIdx.x;
    const int lane = tid & 63;
    const int wid  = tid >> 6;
    const int wm   = wid >> 1;   // 0..1
    const int wn   = wid & 1;    // 0..1
    const int m0   = blockIdx.y * 128;
    const int n0   = blockIdx.x * 128;

    f32x4 acc[4][4] = {};

    const int r_in  = lane >> 3;       // 0..7 row within wave's 8-row strip
    const int s_lds = lane & 7;        // 0..7 16B slot within row

    for (int k0 = 0; k0 < K; k0 += 64) {
        #pragma unroll
        for (int j = 0; j < 4; ++j) {
            const int rbase = j * 32 + wid * 8;       // wave-uniform
            const int r     = rbase + r_in;
            const int s_g   = s_lds ^ (r & 7);        // pre-swizzled global source
            const _Float16* ga = A  + (size_t)(m0 + r) * K + k0 + s_g * 8;
            const _Float16* gb = Bw + (size_t)(n0 + r) * K + k0 + s_g * 8;
            __builtin_amdgcn_global_load_lds((gq_t)(const void*)ga,
                                             (lq_t)(void*)(As + rbase * 64), 16, 0, 0);
            __builtin_amdgcn_global_load_lds((gq_t)(const void*)gb,
                                             (lq_t)(void*)(Bs + rbase * 64), 16, 0, 0);
        }
        __syncthreads();

        const int g = lane >> 4;              // k-group 0..3
        #pragma unroll
        for (int kk = 0; kk < 2; ++kk) {
            f16x8 af[4], bf[4];
            #pragma unroll
            for (int mi = 0; mi < 4; ++mi) {
                const int row  = wm * 64 + mi * 16 + (lane & 15);
                const int slot = (kk * 4 + g) ^ (row & 7);
                af[mi] = *(const f16x8*)&As[row * 64 + slot * 8];
            }
            #pragma unroll
            for (int ni = 0; ni < 4; ++ni) {
                const int row  = wn * 64 + ni * 16 + (lane & 15);
                const int slot = (kk * 4 + g) ^ (row & 7);
                bf[ni] = *(const f16x8*)&Bs[row * 64 + slot * 8];
            }
            #pragma unroll
            for (int mi = 0; mi < 4; ++mi)
                #pragma unroll
                for (int ni = 0; ni < 4; ++ni)
                    acc[mi][ni] = __builtin_amdgcn_mfma_f32_16x16x32_f16(
                        af[mi], bf[ni], acc[mi][ni], 0, 0, 0);
        }
        __syncthreads();
    }

    #pragma unroll
    for (int ni = 0; ni < 4; ++ni) {
        const int col = n0 + wn * 64 + ni * 16 + (lane & 15);
        const float bv = bias[col];
        #pragma unroll
        for (int mi = 0; mi < 4; ++mi) {
            const int rowb = m0 + wm * 64 + mi * 16 + (lane >> 4) * 4;
            #pragma unroll
            for (int q = 0; q < 4; ++q) {
                const float val = acc[mi][ni][q] + bv;
                C[(size_t)(rowb + q) * N + col] = (OutT)val;
            }
        }
    }
}

// --------------------------------------------------------------- attention
// Per token: q,k,v in [16][64]; scores = (q*scale)@k^T / 8; softmax over t;
// out = attn @ v.  8 tokens/block, 128 threads: thread = (token, head-row h).
// BW-bound (~21us ~= 131MB floor); packed math measured neutral but kept.
__global__ __launch_bounds__(128, 2)
void attn_kernel(const _Float16* __restrict__ qkv, const float* __restrict__ scale,
                 _Float16* __restrict__ out)
{
    __shared__ _Float16 kv[8][2048];   // per token: k[0..1024), v[1024..2048)
    __shared__ _Float16 sc2[64];       // scale * 0.125 in f16

    const int tid  = threadIdx.x;
    const int tok0 = blockIdx.x * 8;

    if (tid < 64) sc2[tid] = (_Float16)(scale[tid] * 0.125f);

    #pragma unroll
    for (int it = 0; it < 16; ++it) {
        const int vid = tid + it * 128;
        const int tok = vid >> 8;
        const int ofs = (vid & 255) * 8;
        *(f16x8*)&kv[tok][ofs] =
            *(const f16x8*)&qkv[(size_t)(tok0 + tok) * 3072 + 1024 + ofs];
    }
    __syncthreads();

    const int tok = tid >> 4;
    const int h   = tid & 15;
    const size_t qbase = (size_t)(tok0 + tok) * 3072 + h * 64;

    f16x2 q2[32];
    #pragma unroll
    for (int d0 = 0; d0 < 8; ++d0) {
        f16x8 qv = *(const f16x8*)&qkv[qbase + d0 * 8];
        f16x8 sv = *(const f16x8*)&sc2[d0 * 8];
        #pragma unroll
        for (int j = 0; j < 4; ++j) {
            f16x2 t;
            t[0] = qv[2 * j]     * sv[2 * j];
            t[1] = qv[2 * j + 1] * sv[2 * j + 1];
            q2[d0 * 4 + j] = t;
        }
    }

    float s[16];
    #pragma unroll
    for (int t = 0; t < 16; ++t) {
        float a = 0.f;
        #pragma unroll
        for (int p = 0; p < 32; ++p) {
            f16x2 kp = *(const f16x2*)&kv[tok][t * 64 + p * 2];
            a = __builtin_amdgcn_fdot2(q2[p], kp, a, false);
        }
        s[t] = a;
    }

    float mx = s[0];
    #pragma unroll
    for (int t = 1; t < 16; ++t) mx = fmaxf(mx, s[t]);
    float sum = 0.f;
    #pragma unroll
    for (int t = 0; t < 16; ++t) { s[t] = __expf(s[t] - mx); sum += s[t]; }
    const float inv = 1.f / sum;

    f16x2 o2[32] = {};
    #pragma unroll
    for (int t = 0; t < 16; ++t) {
        const _Float16 aw = (_Float16)(s[t] * inv);
        f16x2 aw2; aw2[0] = aw; aw2[1] = aw;
        #pragma unroll
        for (int p = 0; p < 32; ++p) {
            f16x2 vp = *(const f16x2*)&kv[tok][1024 + t * 64 + p * 2];
            o2[p] += aw2 * vp;     // v_pk_fma_f16
        }
    }

    #pragma unroll
    for (int d0 = 0; d0 < 8; ++d0) {
        f16x8 ov;
        #pragma unroll
        for (int j = 0; j < 4; ++j) { ov[2*j] = o2[d0*4+j][0]; ov[2*j+1] = o2[d0*4+j][1]; }
        *(f16x8*)&out[(size_t)(tok0 + tok) * 1024 + h * 64 + d0 * 8] = ov;
    }
}

// ----------------------------------------------------------------- launcher
extern "C" void kernel_launch(void* const* d_in, const int* in_sizes, int n_in,
                              void* d_out, int out_size, void* d_ws, size_t ws_size,
                              hipStream_t stream)
{
    const float* x     = (const float*)d_in[0];
    const float* Wq    = (const float*)d_in[1];
    const float* bq    = (const float*)d_in[2];
    const float* Wk    = (const float*)d_in[3];
    const float* bk    = (const float*)d_in[4];
    const float* Wv    = (const float*)d_in[5];
    const float* bv    = (const float*)d_in[6];
    const float* Wo    = (const float*)d_in[7];
    const float* bo    = (const float*)d_in[8];
    const float* scale = (const float*)d_in[9];
    float* out = (float*)d_out;

    const int M = in_sizes[0] / HID;   // 16384 tokens

    char* ws = (char*)d_ws;
    _Float16* x16    = (_Float16*)ws;
    _Float16* attn16 = x16;
    _Float16* wqkv16 = (_Float16*)(ws + (size_t)M * HID * 2);
    _Float16* wo16   = wqkv16 + (size_t)3 * HID * HID;
    float*    bqkv   = (float*)(wo16 + (size_t)HID * HID);
    _Float16* qkv16  = (_Float16*)((char*)bqkv + 3 * HID * 4);

    cvt_all<<<4096, 256, 0, stream>>>(x, Wq, Wk, Wv, Wo, bq, bk, bv,
                                      x16, wqkv16, wo16, bqkv,
                                      M * HID / 8, HID * HID / 8);

    // QKV GEMM: [M,1024] @ [3072,1024]^T -> qkv16 [M,3072] (f16)
    gemm_bt<_Float16><<<dim3(3 * HID / 128, M / 128), 256, 0, stream>>>(
        x16, wqkv16, bqkv, qkv16, M, 3 * HID, HID);

    // per-token head-mix attention -> attn16 [M,1024] (f16)
    attn_kernel<<<M / 8, 128, 0, stream>>>(qkv16, scale, attn16);

    // output GEMM: [M,1024] @ [1024,1024]^T + bo -> out (f32)
    gemm_bt<float><<<dim3(HID / 128, M / 128), 256, 0, stream>>>(
        attn16, wo16, bo, out, M, HID, HID);
}